// Round 1
// baseline (152.213 us; speedup 1.0000x reference)
//
#include <hip/hip_runtime.h>

// HomoHingeLoss: loss.mean() over [n,h,w,i,j] of
//   250 * s * max(1 - dot, 0) + (1-s) * max(dot - 0.2, 0)
// where dot[n,p1,p2] = sum_c desc1[n,c,p1] * desc2[n,c,p2]  (P = H*W)
// and s = (|| grid[p1] - warp(grid[p2]) || <= 7.5)
//
// Strategy: batched A^T*B GEMM (f32, tiled LDS) with fused epilogue and
// deterministic two-stage reduction. Warped grid precomputed (3072 pts).

#define GS 8
#define POS_LAMBDA 250.0f
#define POS_MARGIN 1.0f
#define NEG_MARGIN 0.2f
#define N_ 2
#define C_ 256
#define H_ 48
#define W_ 64
#define P_ (H_ * W_)              // 3072
#define TILE 64
#define KB 16
#define TILES_1D (P_ / TILE)      // 48
#define TILES_PER_N (TILES_1D * TILES_1D)  // 2304
#define NBLOCKS (N_ * TILES_PER_N)         // 4608
#define R2_THRESH 56.25f          // (GS - 0.5)^2

// ---------------------------------------------------------------------------
// Kernel 1: warp the 3072 cell-center grid points by the homography.
// wg[2*p] = wx, wg[2*p+1] = wy
__global__ __launch_bounds__(256) void wgrid_kernel(const float* __restrict__ homo,
                                                    float* __restrict__ wg) {
    int p = blockIdx.x * 256 + threadIdx.x;
    if (p >= P_) return;
    float gx = (float)((p & (W_ - 1)) * GS + GS / 2);
    float gy = (float)((p >> 6) * GS + GS / 2);
    float h0 = homo[0], h1 = homo[1], h2 = homo[2];
    float h3 = homo[3], h4 = homo[4], h5 = homo[5];
    float h6 = homo[6], h7 = homo[7], h8 = homo[8];
    float w0 = fmaf(h0, gx, fmaf(h1, gy, h2));
    float w1 = fmaf(h3, gx, fmaf(h4, gy, h5));
    float w2 = fmaf(h6, gx, fmaf(h7, gy, h8));
    wg[2 * p]     = w0 / w2;
    wg[2 * p + 1] = w1 / w2;
}

// ---------------------------------------------------------------------------
// Kernel 2: per-block 64x64 output tile of A^T*B with fused hinge-loss
// epilogue; one partial sum per block.
__global__ __launch_bounds__(256) void hinge_gemm_kernel(const float* __restrict__ d1,
                                                         const float* __restrict__ d2,
                                                         const float* __restrict__ wg,
                                                         float* __restrict__ partial) {
    const int bid = blockIdx.x;
    const int n   = bid / TILES_PER_N;
    const int rem = bid % TILES_PER_N;
    const int bp1 = (rem / TILES_1D) * TILE;   // rows  (desc1 / h,w side)
    const int bp2 = (rem % TILES_1D) * TILE;   // cols  (desc2 / i,j side)

    const float* __restrict__ A = d1 + (size_t)n * C_ * P_;
    const float* __restrict__ B = d2 + (size_t)n * C_ * P_;

    __shared__ float As[KB][TILE];
    __shared__ float Bs[KB][TILE];

    const int t  = threadIdx.x;
    const int tx = t & 15;        // 0..15 -> p2 group
    const int ty = t >> 4;        // 0..15 -> p1 group

    float acc[4][4] = {};

    for (int k0 = 0; k0 < C_; k0 += KB) {
        if (k0) __syncthreads();
#pragma unroll
        for (int l = 0; l < 4; ++l) {
            int idx = t + l * 256;
            int r = idx >> 6;       // 0..15
            int cc = idx & 63;      // 0..63
            As[r][cc] = A[(size_t)(k0 + r) * P_ + bp1 + cc];
            Bs[r][cc] = B[(size_t)(k0 + r) * P_ + bp2 + cc];
        }
        __syncthreads();
#pragma unroll
        for (int k = 0; k < KB; ++k) {
            float4 av = *(const float4*)&As[k][ty * 4];
            float4 bv = *(const float4*)&Bs[k][tx * 4];
            float a0 = av.x, a1 = av.y, a2 = av.z, a3 = av.w;
            float b0 = bv.x, b1 = bv.y, b2 = bv.z, b3 = bv.w;
            acc[0][0] = fmaf(a0, b0, acc[0][0]);
            acc[0][1] = fmaf(a0, b1, acc[0][1]);
            acc[0][2] = fmaf(a0, b2, acc[0][2]);
            acc[0][3] = fmaf(a0, b3, acc[0][3]);
            acc[1][0] = fmaf(a1, b0, acc[1][0]);
            acc[1][1] = fmaf(a1, b1, acc[1][1]);
            acc[1][2] = fmaf(a1, b2, acc[1][2]);
            acc[1][3] = fmaf(a1, b3, acc[1][3]);
            acc[2][0] = fmaf(a2, b0, acc[2][0]);
            acc[2][1] = fmaf(a2, b1, acc[2][1]);
            acc[2][2] = fmaf(a2, b2, acc[2][2]);
            acc[2][3] = fmaf(a2, b3, acc[2][3]);
            acc[3][0] = fmaf(a3, b0, acc[3][0]);
            acc[3][1] = fmaf(a3, b1, acc[3][1]);
            acc[3][2] = fmaf(a3, b2, acc[3][2]);
            acc[3][3] = fmaf(a3, b3, acc[3][3]);
        }
    }

    // Epilogue: hinge loss with spatial mask.
    float wx[4], wy[4];
#pragma unroll
    for (int j = 0; j < 4; ++j) {
        int p2 = bp2 + tx * 4 + j;
        wx[j] = wg[2 * p2];
        wy[j] = wg[2 * p2 + 1];
    }

    float lsum = 0.0f;
#pragma unroll
    for (int i = 0; i < 4; ++i) {
        int p1 = bp1 + ty * 4 + i;
        float gx1 = (float)((p1 & (W_ - 1)) * GS + GS / 2);
        float gy1 = (float)((p1 >> 6) * GS + GS / 2);
#pragma unroll
        for (int j = 0; j < 4; ++j) {
            float dx = gx1 - wx[j];
            float dy = gy1 - wy[j];
            float r2 = fmaf(dx, dx, dy * dy);
            float dot = acc[i][j];
            float pos = fmaxf(POS_MARGIN - dot, 0.0f);
            float neg = fmaxf(dot - NEG_MARGIN, 0.0f);
            lsum += (r2 <= R2_THRESH) ? POS_LAMBDA * pos : neg;
        }
    }

    // Block reduction: wave shuffle then cross-wave LDS.
#pragma unroll
    for (int off = 32; off > 0; off >>= 1)
        lsum += __shfl_down(lsum, off, 64);

    __shared__ float red[4];
    int wave = t >> 6, lane = t & 63;
    if (lane == 0) red[wave] = lsum;
    __syncthreads();
    if (t == 0) partial[bid] = red[0] + red[1] + red[2] + red[3];
}

// ---------------------------------------------------------------------------
// Kernel 3: deterministic final reduction of the 4608 partials -> mean.
__global__ __launch_bounds__(256) void reduce_kernel(const float* __restrict__ partial,
                                                     float* __restrict__ out) {
    __shared__ double sd[256];
    int t = threadIdx.x;
    double s = 0.0;
    for (int i = t; i < NBLOCKS; i += 256) s += (double)partial[i];
    sd[t] = s;
    __syncthreads();
    for (int off = 128; off > 0; off >>= 1) {
        if (t < off) sd[t] += sd[t + off];
        __syncthreads();
    }
    if (t == 0) {
        double cnt = (double)N_ * (double)P_ * (double)P_;
        out[0] = (float)(sd[0] / cnt);
    }
}

// ---------------------------------------------------------------------------
extern "C" void kernel_launch(void* const* d_in, const int* in_sizes, int n_in,
                              void* d_out, int out_size, void* d_ws, size_t ws_size,
                              hipStream_t stream) {
    const float* desc1 = (const float*)d_in[0];
    const float* desc2 = (const float*)d_in[1];
    const float* homo  = (const float*)d_in[2];
    float* out = (float*)d_out;

    float* partial = (float*)d_ws;            // NBLOCKS floats
    float* wg      = partial + NBLOCKS;       // 2*P_ floats

    wgrid_kernel<<<(P_ + 255) / 256, 256, 0, stream>>>(homo, wg);
    hinge_gemm_kernel<<<NBLOCKS, 256, 0, stream>>>(desc1, desc2, wg, partial);
    reduce_kernel<<<1, 256, 0, stream>>>(partial, out);
}

// Round 2
// 39.343 us; speedup vs baseline: 3.8689x; 3.8689x over previous
//
#include <hip/hip_runtime.h>

// HomoHingeLoss via bf16 MFMA GEMM with fused hinge epilogue.
// dot[n,p1,p2] = sum_c desc1[n,c,p1]*desc2[n,c,p2], P=3072, C=256, batch 2.
// Pipeline: wgrid -> f32->bf16 transpose-convert ([n][p][c]) -> MFMA GEMM
// (128x128 tile, BK=64, global_load_lds + XOR swizzle) -> partials -> reduce.

#define GS 8
#define POS_LAMBDA 250.0f
#define POS_MARGIN 1.0f
#define NEG_MARGIN 0.2f
#define N_ 2
#define C_ 256
#define H_ 48
#define W_ 64
#define P_ (H_ * W_)               // 3072
#define R2_THRESH 56.25f           // (8 - 0.5)^2

#define BM 128
#define BN 128
#define BK 64
#define TM (P_ / BM)               // 24
#define TN (P_ / BN)               // 24
#define GEMM_BLOCKS (N_ * TM * TN) // 1152

typedef __attribute__((ext_vector_type(8))) short short8;
typedef __attribute__((ext_vector_type(4))) float floatx4;

__device__ __forceinline__ unsigned short f32_to_bf16(float f) {
    unsigned u = __builtin_bit_cast(unsigned, f);
    unsigned r = (u + 0x7FFFu + ((u >> 16) & 1u)) >> 16;   // RNE
    return (unsigned short)r;
}

__device__ __forceinline__ void load16_to_lds(const void* g, void* l) {
    __builtin_amdgcn_global_load_lds(
        (const __attribute__((address_space(1))) void*)g,
        (__attribute__((address_space(3))) void*)l, 16, 0, 0);
}

// ---------------------------------------------------------------------------
// Kernel 1: warp the 3072 cell-center grid points by the homography.
__global__ __launch_bounds__(256) void wgrid_kernel(const float* __restrict__ homo,
                                                    float* __restrict__ wg) {
    int p = blockIdx.x * 256 + threadIdx.x;
    if (p >= P_) return;
    float gx = (float)((p & (W_ - 1)) * GS + GS / 2);
    float gy = (float)((p >> 6) * GS + GS / 2);
    float h0 = homo[0], h1 = homo[1], h2 = homo[2];
    float h3 = homo[3], h4 = homo[4], h5 = homo[5];
    float h6 = homo[6], h7 = homo[7], h8 = homo[8];
    float w0 = fmaf(h0, gx, fmaf(h1, gy, h2));
    float w1 = fmaf(h3, gx, fmaf(h4, gy, h5));
    float w2 = fmaf(h6, gx, fmaf(h7, gy, h8));
    wg[2 * p]     = w0 / w2;
    wg[2 * p + 1] = w1 / w2;
}

// ---------------------------------------------------------------------------
// Kernel 2: f32 [n][c][p] -> bf16 [n][p][c] (transpose + convert), 64x64 tiles.
__global__ __launch_bounds__(256) void conv_kernel(const float* __restrict__ in1,
                                                   const float* __restrict__ in2,
                                                   unsigned short* __restrict__ o1,
                                                   unsigned short* __restrict__ o2) {
    int bid = blockIdx.x;                 // 768 blocks: 2 descs x 2 n x 48 p x 4 c
    int d = bid & 1;
    int r = bid >> 1;                     // 0..383
    int n = r / (48 * 4);
    int r2 = r % (48 * 4);
    int pt = r2 >> 2;                     // p-tile 0..47
    int ct = r2 & 3;                      // c-tile 0..3
    const float* src = (d ? in2 : in1) + ((size_t)n * C_ + ct * 64) * P_ + pt * 64;
    unsigned short* dst = (d ? o2 : o1) + ((size_t)n * P_ + (size_t)pt * 64) * C_ + ct * 64;

    __shared__ unsigned short tile[64][72];   // [p][c], padded (144 B rows, 16B-aligned)

    int t = threadIdx.x;
#pragma unroll
    for (int i = 0; i < 4; ++i) {
        int idx = t + i * 256;            // 0..1023
        int c = idx >> 4;                 // 0..63
        int p4 = (idx & 15) << 2;         // 0,4,...,60
        float4 v = *(const float4*)(src + (size_t)c * P_ + p4);
        tile[p4 + 0][c] = f32_to_bf16(v.x);
        tile[p4 + 1][c] = f32_to_bf16(v.y);
        tile[p4 + 2][c] = f32_to_bf16(v.z);
        tile[p4 + 3][c] = f32_to_bf16(v.w);
    }
    __syncthreads();
#pragma unroll
    for (int i = 0; i < 2; ++i) {
        int idx = t + i * 256;            // 0..511
        int p = idx >> 3;                 // 0..63
        int c8 = (idx & 7) << 3;          // 0,8,...,56
        *(short8*)(dst + (size_t)p * C_ + c8) = *(const short8*)&tile[p][c8];
    }
}

// ---------------------------------------------------------------------------
// Kernel 3: MFMA GEMM tile 128x128, BK=64, fused hinge epilogue.
// LDS: A tile [128 rows][64 c] linear 16KB + B tile 16KB. XOR swizzle:
// logical 16B-slot q at row r lives at slot q^(r&7)  (rule-21 both-sides).
__global__ __launch_bounds__(256) void mfma_hinge_kernel(const unsigned short* __restrict__ bf1,
                                                         const unsigned short* __restrict__ bf2,
                                                         const float* __restrict__ wg,
                                                         float* __restrict__ partial) {
    __shared__ __attribute__((aligned(16))) char smem[32768];
    __shared__ float red[4];

    const int bid = blockIdx.x;
    const int n   = bid / (TM * TN);
    const int rem = bid % (TM * TN);
    const int bp1 = (rem / TN) * BM;
    const int bp2 = (rem % TN) * BN;
    const unsigned short* A = bf1 + (size_t)n * P_ * C_;
    const unsigned short* B = bf2 + (size_t)n * P_ * C_;

    const int t    = threadIdx.x;
    const int lane = t & 63;
    const int wv   = t >> 6;      // 0..3
    const int wr   = wv >> 1;     // p1 quadrant
    const int wc   = wv & 1;      // p2 quadrant

    floatx4 acc[4][4];
#pragma unroll
    for (int i = 0; i < 4; ++i)
#pragma unroll
        for (int j = 0; j < 4; ++j)
            acc[i][j] = floatx4{0.0f, 0.0f, 0.0f, 0.0f};

    const int sub  = lane >> 3;   // row-within-chunk 0..7
    const int slot = lane & 7;    // 16B slot 0..7

    for (int k0 = 0; k0 < C_; k0 += BK) {
        if (k0) __syncthreads();
        // stage: 16 chunks of 1KB per tile; wave wv owns chunks wv*4+i.
#pragma unroll
        for (int i = 0; i < 4; ++i) {
            int chunk = wv * 4 + i;
            int row = chunk * 8 + sub;
            int c16 = slot ^ (row & 7);                    // inverse-swizzled source
            load16_to_lds((const char*)(A + (size_t)(bp1 + row) * C_ + k0) + c16 * 16,
                          smem + chunk * 1024);
        }
#pragma unroll
        for (int i = 0; i < 4; ++i) {
            int chunk = wv * 4 + i;
            int row = chunk * 8 + sub;
            int c16 = slot ^ (row & 7);
            load16_to_lds((const char*)(B + (size_t)(bp2 + row) * C_ + k0) + c16 * 16,
                          smem + 16384 + chunk * 1024);
        }
        __syncthreads();

#pragma unroll
        for (int kk = 0; kk < 2; ++kk) {
            short8 af[4], bfr[4];
#pragma unroll
            for (int i = 0; i < 4; ++i) {
                int row = wr * 64 + i * 16 + (lane & 15);
                int q   = kk * 4 + (lane >> 4);
                int off = row * 128 + ((q ^ (row & 7)) << 4);   // swizzled read
                af[i] = *(const short8*)(smem + off);
            }
#pragma unroll
            for (int j = 0; j < 4; ++j) {
                int row = wc * 64 + j * 16 + (lane & 15);
                int q   = kk * 4 + (lane >> 4);
                int off = row * 128 + ((q ^ (row & 7)) << 4);
                bfr[j] = *(const short8*)(smem + 16384 + off);
            }
#pragma unroll
            for (int i = 0; i < 4; ++i)
#pragma unroll
                for (int j = 0; j < 4; ++j)
                    acc[i][j] = __builtin_amdgcn_mfma_f32_16x16x32_bf16(af[i], bfr[j],
                                                                        acc[i][j], 0, 0, 0);
        }
    }

    // Epilogue: D mapping col=lane&15, row=(lane>>4)*4+reg (m89-verified).
    const int col   = lane & 15;
    const int rbase = (lane >> 4) * 4;
    float lsum = 0.0f;
#pragma unroll
    for (int j = 0; j < 4; ++j) {
        int p2 = bp2 + wc * 64 + j * 16 + col;
        float wx = wg[2 * p2], wy = wg[2 * p2 + 1];
#pragma unroll
        for (int i = 0; i < 4; ++i) {
            int p1b = bp1 + wr * 64 + i * 16 + rbase;
#pragma unroll
            for (int r = 0; r < 4; ++r) {
                int p1 = p1b + r;
                float gx = (float)((p1 & (W_ - 1)) * GS + GS / 2);
                float gy = (float)((p1 >> 6) * GS + GS / 2);
                float dx = gx - wx, dy = gy - wy;
                float r2 = fmaf(dx, dx, dy * dy);
                float dot = acc[i][j][r];
                float pos = fmaxf(POS_MARGIN - dot, 0.0f);
                float neg = fmaxf(dot - NEG_MARGIN, 0.0f);
                lsum += (r2 <= R2_THRESH) ? POS_LAMBDA * pos : neg;
            }
        }
    }

#pragma unroll
    for (int off = 32; off > 0; off >>= 1)
        lsum += __shfl_down(lsum, off, 64);
    if (lane == 0) red[wv] = lsum;
    __syncthreads();
    if (t == 0) partial[bid] = red[0] + red[1] + red[2] + red[3];
}

// ---------------------------------------------------------------------------
// Kernel 4: deterministic final reduction -> mean.
__global__ __launch_bounds__(256) void reduce_kernel(const float* __restrict__ partial,
                                                     float* __restrict__ out) {
    __shared__ double sd[256];
    int t = threadIdx.x;
    double s = 0.0;
    for (int i = t; i < GEMM_BLOCKS; i += 256) s += (double)partial[i];
    sd[t] = s;
    __syncthreads();
    for (int off = 128; off > 0; off >>= 1) {
        if (t < off) sd[t] += sd[t + off];
        __syncthreads();
    }
    if (t == 0) {
        double cnt = (double)N_ * (double)P_ * (double)P_;
        out[0] = (float)(sd[0] / cnt);
    }
}

// ---------------------------------------------------------------------------
extern "C" void kernel_launch(void* const* d_in, const int* in_sizes, int n_in,
                              void* d_out, int out_size, void* d_ws, size_t ws_size,
                              hipStream_t stream) {
    const float* desc1 = (const float*)d_in[0];
    const float* desc2 = (const float*)d_in[1];
    const float* homo  = (const float*)d_in[2];
    float* out = (float*)d_out;

    unsigned short* b1 = (unsigned short*)d_ws;                 // N*P*C bf16
    unsigned short* b2 = b1 + (size_t)N_ * P_ * C_;             // N*P*C bf16
    float* partial = (float*)(b2 + (size_t)N_ * P_ * C_);       // 1152 f32
    float* wgbuf   = partial + GEMM_BLOCKS;                     // 2*P f32

    wgrid_kernel<<<(P_ + 255) / 256, 256, 0, stream>>>(homo, wgbuf);
    conv_kernel<<<768, 256, 0, stream>>>(desc1, desc2, b1, b2);
    mfma_hinge_kernel<<<GEMM_BLOCKS, 256, 0, stream>>>(b1, b2, wgbuf, partial);
    reduce_kernel<<<1, 256, 0, stream>>>(partial, out);
}